// Round 1
// 183.251 us; speedup vs baseline: 1.3144x; 1.3144x over previous
//
#include <hip/hip_runtime.h>
#include <stdint.h>

// Problem constants (fixed by the reference)
#define BB   2
#define SS   2048
#define DD   768
#define HH   12
#define MM   (BB*SS)          // 4096 rows in all GEMMs
#define XSZ  (MM*DD)          // 3,145,728
#define WSZ  (DD*DD)          //   589,824

typedef __bf16 v8bf __attribute__((ext_vector_type(8)));   // 8 bf16 = 4 VGPRs (MFMA A/B frag)
typedef float  v4f  __attribute__((ext_vector_type(4)));   // MFMA C/D frag (16x16)

__device__ inline v4f mfma16(v8bf a, v8bf b, v4f c) {
    return __builtin_amdgcn_mfma_f32_16x16x32_bf16(a, b, c, 0, 0, 0);
}

// float -> bf16 bits, round-to-nearest-even
__device__ inline unsigned short f2bf(float f) {
    union { float f; uint32_t u; } v; v.f = f;
    return (unsigned short)((v.u + 0x7FFFu + ((v.u >> 16) & 1u)) >> 16);
}

// 8 contiguous fp32 -> 8 bf16 packed into 16 bytes (VGPR staging path)
__device__ inline uint4 cvt8(const float* __restrict__ p) {
    uint4 out;
    unsigned short* s = (unsigned short*)&out;
#pragma unroll
    for (int j = 0; j < 8; ++j) s[j] = f2bf(p[j]);
    return out;
}

// Async 16B global->LDS copy (gfx950). LDS dest is wave-uniform base + lane*16B.
__device__ __forceinline__ void gld_lds16(const unsigned short* g, unsigned short* l) {
    __builtin_amdgcn_global_load_lds(
        (const __attribute__((address_space(1))) void*)g,
        (__attribute__((address_space(3))) void*)l, 16, 0, 0);
}

// ---------------------------------------------------------------------------
// fp32 -> bf16 for Wq,Wk,Wv into d_out's second half (3*WSZ elems = 1728 blocks
// x 256 thr x 4 elems exactly). That region is dead until gemm3 overwrites it.
// ---------------------------------------------------------------------------
__global__ __launch_bounds__(256) void cvt_w3(
    const float* __restrict__ Wq, const float* __restrict__ Wk,
    const float* __restrict__ Wv, unsigned short* __restrict__ dst)
{
    long i4 = ((long)blockIdx.x * 256 + threadIdx.x) * 4;
    int t = (int)(i4 / WSZ);
    long off = i4 - (long)t * WSZ;
    const float* s = (t == 0) ? Wq : (t == 1) ? Wk : Wv;
    float4 v = *(const float4*)(s + off);
    ushort4 o;
    o.x = f2bf(v.x); o.y = f2bf(v.y); o.z = f2bf(v.z); o.w = f2bf(v.w);
    *(ushort4*)(dst + (size_t)t * WSZ + off) = o;
}

// ---------------------------------------------------------------------------
// NT GEMM, 64x64 tile (R14: grid-starvation fix). BK=32, 4 waves 2x2, each wave
// 32x32 (acc 2x2). Staging per K-iter: As/Bs 2048 elems each = 1 uint4/thread.
// A_ASYNC/W_ASYNC: bf16 via global_load_lds | fp32 via cvt8 (both verified).
// C_F32: fp32 epilogue. VT2: z==2 writes V transposed (B,H,64,S).
// ---------------------------------------------------------------------------
template<int A_ASYNC, int W_ASYNC, int C_F32, int VT2>
__global__ __launch_bounds__(256) void gemm_64(
    const void* __restrict__ Ain,
    const void* __restrict__ W0, const void* __restrict__ W1,
    const void* __restrict__ W2,
    void* __restrict__ C0, void* __restrict__ C1, void* __restrict__ C2)
{
    const int K = DD, N = DD;
    const void* W = W0;
    void* C = C0;
    if (blockIdx.z == 1) { W = W1; C = C1; }
    else if (blockIdx.z == 2) { W = W2; C = C2; }

    __shared__ __align__(16) unsigned short As[64 * 32];
    __shared__ __align__(16) unsigned short Bs[64 * 32];

    const int tid  = threadIdx.x;
    const int wave = tid >> 6, lane = tid & 63;
    const int quad = lane >> 4, l16 = lane & 15;
    const int waveM = (wave >> 1) * 32, waveN = (wave & 1) * 32;
    const int m0 = blockIdx.y * 64, n0 = blockIdx.x * 64;

    const int rS = (tid >> 2), cS = (tid & 3) * 8;   // e = tid*8 -> row, col in 64x32 tile

    v4f acc[2][2] = {};

    for (int kt = 0; kt < K; kt += 32) {
        __syncthreads();
        if (A_ASYNC)
            gld_lds16((const unsigned short*)Ain + (size_t)(m0 + rS) * K + kt + cS,
                      &As[wave * 512]);
        else
            *(uint4*)(&As[tid * 8]) = cvt8((const float*)Ain + (size_t)(m0 + rS) * K + kt + cS);
        if (W_ASYNC)
            gld_lds16((const unsigned short*)W + (size_t)(n0 + rS) * K + kt + cS,
                      &Bs[wave * 512]);
        else
            *(uint4*)(&Bs[tid * 8]) = cvt8((const float*)W + (size_t)(n0 + rS) * K + kt + cS);
        __syncthreads();   // drains vm + ds for staging

        v8bf af[2], bf[2];
#pragma unroll
        for (int i = 0; i < 2; ++i) {
            af[i] = *(const v8bf*)(&As[(waveM + i * 16 + l16) * 32 + quad * 8]);
            bf[i] = *(const v8bf*)(&Bs[(waveN + i * 16 + l16) * 32 + quad * 8]);
        }
#pragma unroll
        for (int mi = 0; mi < 2; ++mi)
#pragma unroll
            for (int ni = 0; ni < 2; ++ni)
                acc[mi][ni] = mfma16(af[mi], bf[ni], acc[mi][ni]);
    }

    // Epilogue: C/D layout col=l16, row=quad*4+r (verified formula)
#pragma unroll
    for (int mi = 0; mi < 2; ++mi)
#pragma unroll
        for (int ni = 0; ni < 2; ++ni)
#pragma unroll
            for (int r = 0; r < 4; ++r) {
                int row = m0 + waveM + mi * 16 + quad * 4 + r;
                int col = n0 + waveN + ni * 16 + l16;
                if (VT2 && blockIdx.z == 2) {
                    int b = row >> 11, s = row & 2047;
                    int h = col >> 6,  dk = col & 63;
                    ((unsigned short*)C)[(((size_t)(b * HH + h)) * 64 + dk) * SS + s] =
                        f2bf(acc[mi][ni][r]);
                } else if (C_F32) {
                    ((float*)C)[(size_t)row * N + col] = acc[mi][ni][r];
                } else {
                    ((unsigned short*)C)[(size_t)row * N + col] = f2bf(acc[mi][ni][r]);
                }
            }
}

// ---------------------------------------------------------------------------
// R15 attention rewrite: LDS-staged, wave-private q-strips.
//
// Why: R14's counters (MfmaUtil 5%, VALU 26%, occ 21%, 1200 cyc/tile-issue/CU)
// showed a latency-bound kernel whose register budget (VGPR=88 vs 128 needed
// for kf/nf/vf) forced the compiler to serialize the "prefetch" loads next to
// their uses -> every tile ate full L2 latency, and the k-split gave each wave
// only ~NT/4 consecutive tiles so no pipeline ever filled.
//
// Structure: block = 64 q-rows (4 waves x 16 private rows), grid (H,B,S/64)
// with z-slowest LPT (heavy strips first). Since the block is 64-aligned, all
// 4 waves share the same causal tile count NT = qs/64+1, so K/V tiles are
// staged COOPERATIVELY into double-buffered LDS via global_load_lds (2-phase:
// stage kt+1 async while computing kt; one barrier/tile drains it).
// LDS tiles are XOR-swizzled (byte ^= (row&7)<<4) to make the stride-128B
// ds_read_b128 frag reads bank-conflict-free; since global_load_lds writes
// linearly, the swizzle is applied to the GLOBAL SOURCE address (inverse = same
// XOR) and to the read address (both-sides rule). Each wave runs NT sequential
// tiles and writes its own 16 output rows directly -- no merge phase.
// MFMA fragment math, fixed-base softmax exp(s/8), P round-trip and diagonal
// masking are verbatim from the verified R13/R14 kernel.
// ---------------------------------------------------------------------------
__global__ __launch_bounds__(256, 3) void attn_ls(
    const unsigned short* Q,                 // (B,S,D) bf16 (aliases O)
    const unsigned short* __restrict__ Kg,   // (B,S,D) bf16
    const unsigned short* __restrict__ Vt,   // (B,H,64,S) bf16 transposed
    unsigned short* O)                       // (B,S,D) bf16
{
    const int h = blockIdx.x, b = blockIdx.y;
    const int qs = (SS / 64 - 1 - (int)blockIdx.z) * 64;   // LPT: heavy first
    const int tid  = threadIdx.x;
    const int wave = tid >> 6, lane = tid & 63;
    const int quad = lane >> 4, l16 = lane & 15;
    const int qw = qs + wave * 16;           // this wave's private q rows
    const float scale = 0.125f;              // 1/sqrt(64)

    __shared__ __align__(16) unsigned short Ks[2][4096];   // 2 x 64x64 bf16, swizzled
    __shared__ __align__(16) unsigned short Vs[2][4096];   // 2 x 64x64 bf16, swizzled
    __shared__ __align__(16) unsigned short Ps[4][16 * 72];// per-wave P buffer

    // Q frags for this wave's 16 rows (read before any O write: in-place safe)
    v8bf qf0, qf1;
    {
        const unsigned short* qp = &Q[((size_t)(b * SS + qw + l16)) * DD + h * 64];
        qf0 = *(const v8bf*)(qp + quad * 8);
        qf1 = *(const v8bf*)(qp + 32 + quad * 8);
    }

    const int NT = qs / 64 + 1;              // causal k-tiles, SAME for all 4 waves
    const char* kgb = (const char*)&Kg[(size_t)(b * SS) * DD + h * 64];
    const char* vgb = (const char*)&Vt[((size_t)(b * HH + h) * 64) * SS];

    // Staging geometry: per matrix 8192B = 2 chunks x (4 waves x 64 lanes x 16B).
    // Linear LDS slot s = chunk*4096 + wave*1024 + lane*16 -> tile row rA = s>>7,
    // in-row chunk swizzled by (rA&7). Source address gets the inverse (same XOR).
    const int rA = wave * 8 + (lane >> 3);               // rows rA and rA+32
    const int oA = ((lane & 7) * 16) ^ ((rA & 7) << 4);  // swizzled in-row byte
    const int swz = (l16 & 7) << 4;                      // read-side XOR

    v4f oacc[4] = {};
    float l_run[4] = {0.f, 0.f, 0.f, 0.f};
    unsigned short* pw = &Ps[wave][0];

    // Prologue: stage tile 0 into buffer 0
    gld_lds16((const unsigned short*)(kgb + (size_t)rA        * (DD * 2) + oA), &Ks[0][wave * 512]);
    gld_lds16((const unsigned short*)(kgb + (size_t)(rA + 32) * (DD * 2) + oA), &Ks[0][2048 + wave * 512]);
    gld_lds16((const unsigned short*)(vgb + (size_t)rA        * (SS * 2) + oA), &Vs[0][wave * 512]);
    gld_lds16((const unsigned short*)(vgb + (size_t)(rA + 32) * (SS * 2) + oA), &Vs[0][2048 + wave * 512]);
    __syncthreads();   // drains vmcnt: tile 0 resident

    for (int kt = 0; kt < NT; ++kt) {
        const int cur = kt & 1;
        const int kb  = kt * 64;

        // Async-stage NEXT tile into the other buffer (latency hides under
        // this tile's QK/softmax/PV; end-of-iter barrier drains it).
        if (kt + 1 < NT) {
            const size_t kb2 = (size_t)(kb + 64);
            gld_lds16((const unsigned short*)(kgb + (kb2 + rA)      * (DD * 2) + oA), &Ks[cur ^ 1][wave * 512]);
            gld_lds16((const unsigned short*)(kgb + (kb2 + rA + 32) * (DD * 2) + oA), &Ks[cur ^ 1][2048 + wave * 512]);
            gld_lds16((const unsigned short*)(vgb + (size_t)rA        * (SS * 2) + kb2 * 2 + oA), &Vs[cur ^ 1][wave * 512]);
            gld_lds16((const unsigned short*)(vgb + (size_t)(rA + 32) * (SS * 2) + kb2 * 2 + oA), &Vs[cur ^ 1][2048 + wave * 512]);
        }

        const char* ksb = (const char*)&Ks[cur][0];
        const char* vsb = (const char*)&Vs[cur][0];

        // K frags from swizzled LDS: row = nk*16+l16, cols half*32 + quad*8..
        v8bf kf0[4], kf1[4];
#pragma unroll
        for (int nk = 0; nk < 4; ++nk) {
            const char* krow = ksb + (size_t)(nk * 16 + l16) * 128;
            kf0[nk] = *(const v8bf*)(krow + ((quad * 16) ^ swz));
            kf1[nk] = *(const v8bf*)(krow + ((64 + quad * 16) ^ swz));
        }

        // S = Q K^T (16 q-rows x 64 keys), f32 accumulate
        v4f sacc[4] = {};
#pragma unroll
        for (int nk = 0; nk < 4; ++nk) {
            sacc[nk] = mfma16(qf0, kf0[nk], sacc[nk]);
            sacc[nk] = mfma16(qf1, kf1[nk], sacc[nk]);
        }

        // fixed-base softmax: p = exp(s/8); mask only on the diagonal tile
        const bool diag = (kt == NT - 1);
        float pv[4][4];
#pragma unroll
        for (int nk = 0; nk < 4; ++nk)
#pragma unroll
            for (int r = 0; r < 4; ++r) {
                float p = __expf(sacc[nk][r] * scale);
                if (diag) {
                    int key  = kb + nk * 16 + l16;
                    int qrow = qw + quad * 4 + r;
                    if (key > qrow) p = 0.0f;
                }
                pv[nk][r] = p;
                l_run[r] += p;
            }

        // V frags (LDS reads issued before the P round-trip so their latency
        // overlaps it): row = dt*16+l16, cols kc*32 + quad*8..
        v8bf vf[2][4];
#pragma unroll
        for (int kc = 0; kc < 2; ++kc)
#pragma unroll
            for (int dt = 0; dt < 4; ++dt) {
                const char* vr = vsb + (size_t)(dt * 16 + l16) * 128;
                vf[kc][dt] = *(const v8bf*)(vr + ((kc * 64 + quad * 16) ^ swz));
            }

        // P: C-layout -> per-wave LDS (stride 72) -> A-layout frags
#pragma unroll
        for (int nk = 0; nk < 4; ++nk)
#pragma unroll
            for (int r = 0; r < 4; ++r)
                pw[(quad * 4 + r) * 72 + nk * 16 + l16] = f2bf(pv[nk][r]);
        __asm__ volatile("" ::: "memory");

        v8bf pa0 = *(const v8bf*)(&pw[l16 * 72 + quad * 8]);
        v8bf pa1 = *(const v8bf*)(&pw[l16 * 72 + 32 + quad * 8]);
#pragma unroll
        for (int dt = 0; dt < 4; ++dt) oacc[dt] = mfma16(pa0, vf[0][dt], oacc[dt]);
#pragma unroll
        for (int dt = 0; dt < 4; ++dt) oacc[dt] = mfma16(pa1, vf[1][dt], oacc[dt]);

        // One barrier per tile: (a) all reads of buf[cur] done before it is
        // restaged next iter, (b) drains vmcnt so buf[cur^1] is resident.
        __syncthreads();
    }

    // Row-sum reduce across the 16 l16-lanes of each quad (verified R13 fix)
    for (int off = 1; off < 16; off <<= 1)
#pragma unroll
        for (int r = 0; r < 4; ++r)
            l_run[r] += __shfl_xor(l_run[r], off, 64);

    float inv[4];
#pragma unroll
    for (int r = 0; r < 4; ++r) inv[r] = 1.0f / l_run[r];

    // Direct per-wave store: lane holds O[qw+quad*4+r][dt*16+l16] (C layout).
    unsigned short* ob = &O[((size_t)(b * SS + qw + quad * 4)) * DD + h * 64 + l16];
#pragma unroll
    for (int r = 0; r < 4; ++r)
#pragma unroll
        for (int dt = 0; dt < 4; ++dt)
            ob[(size_t)r * DD + dt * 16] = f2bf(oacc[dt][r] * inv[r]);
}

// ---------------------------------------------------------------------------
extern "C" void kernel_launch(void* const* d_in, const int* in_sizes, int n_in,
                              void* d_out, int out_size, void* d_ws, size_t ws_size,
                              hipStream_t stream)
{
    const float* X  = (const float*)d_in[0];
    const float* Wq = (const float*)d_in[1];
    const float* Wk = (const float*)d_in[2];
    const float* Wv = (const float*)d_in[3];
    const float* Wo = (const float*)d_in[4];
    float* Out = (float*)d_out;

    // d_ws (verified >= 12.6 MB): Qb, Kb bf16.
    // d_out (12.58 MB as 2*XSZ u16 slots): [0,XSZ) = V^T bf16 (dead before
    // gemm3 writes); [XSZ, XSZ+3*WSZ) = bf16 Wq,Wk,Wv (dead after gemm1).
    unsigned short* Qb  = (unsigned short*)d_ws;
    unsigned short* Kb  = Qb + XSZ;
    unsigned short* Vtb = (unsigned short*)d_out;
    unsigned short* Wqb = Vtb + XSZ;
    unsigned short* Wkb = Wqb + WSZ;
    unsigned short* Wvb = Wkb + WSZ;

    dim3 blk(256);
    cvt_w3<<<1728, blk, 0, stream>>>(Wq, Wk, Wv, Wqb);

    dim3 g1(DD / 64, MM / 64, 3);                   // 2304 blocks: QKV projection
    gemm_64<0, 1, 0, 1><<<g1, blk, 0, stream>>>(X, Wqb, Wkb, Wvb, Qb, Kb, Vtb);

    dim3 g2(HH, BB, SS / 64);                       // 768 blocks: LDS-staged attn
    attn_ls<<<g2, blk, 0, stream>>>(Qb, Kb, Vtb, Qb);

    dim3 g3(DD / 64, MM / 64, 1);                   // 768 blocks: out projection
    gemm_64<1, 0, 1, 0><<<g3, blk, 0, stream>>>(Qb, Wo, Wo, Wo, Out, Out, Out);
}

// Round 2
// 158.775 us; speedup vs baseline: 1.5170x; 1.1542x over previous
//
#include <hip/hip_runtime.h>
#include <stdint.h>

// Problem constants (fixed by the reference)
#define BB   2
#define SS   2048
#define DD   768
#define HH   12
#define MM   (BB*SS)          // 4096 rows in all GEMMs
#define XSZ  (MM*DD)          // 3,145,728
#define WSZ  (DD*DD)          //   589,824

typedef __bf16 v8bf __attribute__((ext_vector_type(8)));   // 8 bf16 = 4 VGPRs (MFMA A/B frag)
typedef float  v4f  __attribute__((ext_vector_type(4)));   // MFMA C/D frag (16x16)

__device__ inline v4f mfma16(v8bf a, v8bf b, v4f c) {
    return __builtin_amdgcn_mfma_f32_16x16x32_bf16(a, b, c, 0, 0, 0);
}

// float -> bf16 bits, round-to-nearest-even
__device__ inline unsigned short f2bf(float f) {
    union { float f; uint32_t u; } v; v.f = f;
    return (unsigned short)((v.u + 0x7FFFu + ((v.u >> 16) & 1u)) >> 16);
}

// 8 contiguous fp32 -> 8 bf16 packed into 16 bytes (VGPR staging path)
__device__ inline uint4 cvt8(const float* __restrict__ p) {
    uint4 out;
    unsigned short* s = (unsigned short*)&out;
#pragma unroll
    for (int j = 0; j < 8; ++j) s[j] = f2bf(p[j]);
    return out;
}

// Async 16B global->LDS copy (gfx950). LDS dest is wave-uniform base + lane*16B.
__device__ __forceinline__ void gld_lds16(const unsigned short* g, unsigned short* l) {
    __builtin_amdgcn_global_load_lds(
        (const __attribute__((address_space(1))) void*)g,
        (__attribute__((address_space(3))) void*)l, 16, 0, 0);
}

// ---------------------------------------------------------------------------
// fp32 -> bf16 for Wq,Wk,Wv into d_out's second half (3*WSZ elems = 1728 blocks
// x 256 thr x 4 elems exactly). That region is dead until gemm3 overwrites it.
// ---------------------------------------------------------------------------
__global__ __launch_bounds__(256) void cvt_w3(
    const float* __restrict__ Wq, const float* __restrict__ Wk,
    const float* __restrict__ Wv, unsigned short* __restrict__ dst)
{
    long i4 = ((long)blockIdx.x * 256 + threadIdx.x) * 4;
    int t = (int)(i4 / WSZ);
    long off = i4 - (long)t * WSZ;
    const float* s = (t == 0) ? Wq : (t == 1) ? Wk : Wv;
    float4 v = *(const float4*)(s + off);
    ushort4 o;
    o.x = f2bf(v.x); o.y = f2bf(v.y); o.z = f2bf(v.z); o.w = f2bf(v.w);
    *(ushort4*)(dst + (size_t)t * WSZ + off) = o;
}

// fp32 -> bf16 for Wo into the (dead after attn) Kb slot. 576 x 256 x 4 = WSZ.
__global__ __launch_bounds__(256) void cvt_wo(
    const float* __restrict__ Wo, unsigned short* __restrict__ dst)
{
    long i4 = ((long)blockIdx.x * 256 + threadIdx.x) * 4;
    float4 v = *(const float4*)(Wo + i4);
    ushort4 o;
    o.x = f2bf(v.x); o.y = f2bf(v.y); o.z = f2bf(v.z); o.w = f2bf(v.w);
    *(ushort4*)(dst + i4) = o;
}

// ---------------------------------------------------------------------------
// R16: fused QKV projection GEMM. Q,K,V share the A matrix (X), so one block
// stages the 64x64 A-tile ONCE (cvt8 fp32->bf16, XOR-swizzled ds_write) and
// runs it against 3 weight tiles -> 24 MFMA per wave per BK=64 step instead of
// R15's 4 per BK=32 (A-traffic /3, MFMA:staging ratio x3). Why: R15 counters
// showed g1 at MfmaUtil 8.5%, FETCH 125MB vs 16MB compulsory (X streamed 36x),
// 3.5M LDS bank conflicts (64B rows -> 8-way aliasing on ds_read_b128).
//
// LDS layout: rows are 128B; all tiles XOR-swizzled byte ^= ((row&7)<<4) so
// frag reads are 2-way (free). A is reg-staged (cvt8) with the swizzle applied
// on the ds_write address; B uses global_load_lds (linear dest) with the
// swizzle pre-applied to the GLOBAL SOURCE col (both-sides rule, involution).
// Grid (12,64) = 768 blocks = 3/CU exactly (no tail). XCD-chunked swizzle:
// each XCD gets 8 consecutive m-strips (1.6MB X + 3.5MB W ~ L2-resident).
// Accumulation order per output element is identical to R15 (k ascending in
// 32-chunks) -> numerically unchanged.
// ---------------------------------------------------------------------------
__global__ __launch_bounds__(256) void gemm_qkv(
    const float* __restrict__ X,
    const unsigned short* __restrict__ Wq,
    const unsigned short* __restrict__ Wk,
    const unsigned short* __restrict__ Wv,
    unsigned short* __restrict__ Qo,
    unsigned short* __restrict__ Ko,
    unsigned short* __restrict__ Vo)
{
    __shared__ __align__(16) unsigned short As[64 * 64];
    __shared__ __align__(16) unsigned short Bs[3][64 * 64];

    // XCD-chunked bijective swizzle of the flat block id (768 % 8 == 0):
    // XCD x gets flat ids {x, x+8, ...} -> contiguous strip range x*96..x*96+95.
    const int flat = (int)(blockIdx.y * gridDim.x + blockIdx.x);
    const int sw   = (flat & 7) * 96 + (flat >> 3);
    const int m0   = (sw / 12) * 64;      // 64 m-strips per XCD-chunk of 8
    const int n0   = (sw % 12) * 64;

    const int tid  = threadIdx.x;
    const int wave = tid >> 6, lane = tid & 63;
    const int quad = lane >> 4, l16 = lane & 15;
    const int waveM = (wave >> 1) * 32, waveN = (wave & 1) * 32;

    // A staging: thread -> row rA = tid>>2 (0..63), 16 elems at col cA
    const int rA  = tid >> 2;
    const int cA  = (tid & 3) * 16;             // elem col of first 8-chunk
    const int rxA = (rA & 7) << 4;              // row-XOR (bytes, 16B granule)

    // B staging via gld_lds16: chunk covers rows base + wave*8 + (lane>>3),
    // LDS linear (row = byte>>7). Source col pre-swizzled by row&7 = lane>>3.
    const int rB  = wave * 8 + (lane >> 3);     // 0..31; +32 for 2nd chunk
    const int cB  = ((lane & 7) ^ (lane >> 3)) * 8;   // pre-swizzled col (elems)

    const int swz = (l16 & 7) << 4;             // read-side XOR (bytes)

    v4f acc[3][2][2] = {};

    const float* ap0 = X + (size_t)(m0 + rA) * DD + cA;
    const unsigned short* w0 = Wq + (size_t)(n0 + rB) * DD + cB;
    const unsigned short* w1 = Wk + (size_t)(n0 + rB) * DD + cB;
    const unsigned short* w2 = Wv + (size_t)(n0 + rB) * DD + cB;

    for (int kt = 0; kt < DD; kt += 64) {
        __syncthreads();
        // A: 16 fp32 -> bf16, two swizzled ds_write_b128
        *(uint4*)((char*)As + rA * 128 + ((cA * 2)      ^ rxA)) = cvt8(ap0 + kt);
        *(uint4*)((char*)As + rA * 128 + ((cA * 2 + 16) ^ rxA)) = cvt8(ap0 + kt + 8);
        // B: 3 weights x 2 chunks (each: 4 waves x 1KB, linear LDS dest)
        gld_lds16(w0 + kt,           &Bs[0][wave * 512]);
        gld_lds16(w0 + kt + 32 * DD, &Bs[0][2048 + wave * 512]);
        gld_lds16(w1 + kt,           &Bs[1][wave * 512]);
        gld_lds16(w1 + kt + 32 * DD, &Bs[1][2048 + wave * 512]);
        gld_lds16(w2 + kt,           &Bs[2][wave * 512]);
        gld_lds16(w2 + kt + 32 * DD, &Bs[2][2048 + wave * 512]);
        __syncthreads();   // drains vm (B) + ds (A) staging

        v8bf af[2][2];
#pragma unroll
        for (int mi = 0; mi < 2; ++mi) {
            const char* arow = (const char*)As + (size_t)(waveM + mi * 16 + l16) * 128;
#pragma unroll
            for (int kf = 0; kf < 2; ++kf)
                af[mi][kf] = *(const v8bf*)(arow + ((kf * 64 + quad * 16) ^ swz));
        }
#pragma unroll
        for (int z = 0; z < 3; ++z) {
            v8bf bfr[2][2];
#pragma unroll
            for (int ni = 0; ni < 2; ++ni) {
                const char* brow = (const char*)&Bs[z][0] + (size_t)(waveN + ni * 16 + l16) * 128;
#pragma unroll
                for (int kf = 0; kf < 2; ++kf)
                    bfr[ni][kf] = *(const v8bf*)(brow + ((kf * 64 + quad * 16) ^ swz));
            }
#pragma unroll
            for (int mi = 0; mi < 2; ++mi)
#pragma unroll
                for (int ni = 0; ni < 2; ++ni) {
                    acc[z][mi][ni] = mfma16(af[mi][0], bfr[ni][0], acc[z][mi][ni]);
                    acc[z][mi][ni] = mfma16(af[mi][1], bfr[ni][1], acc[z][mi][ni]);
                }
        }
    }

    // Epilogue: C/D layout col=l16, row=quad*4+r (verified formula).
    // z=0 -> Q (B,S,D); z=1 -> K (B,S,D); z=2 -> V transposed (B,H,64,S).
#pragma unroll
    for (int mi = 0; mi < 2; ++mi)
#pragma unroll
        for (int ni = 0; ni < 2; ++ni)
#pragma unroll
            for (int r = 0; r < 4; ++r) {
                const int row = m0 + waveM + mi * 16 + quad * 4 + r;
                const int col = n0 + waveN + ni * 16 + l16;
                Qo[(size_t)row * DD + col] = f2bf(acc[0][mi][ni][r]);
                Ko[(size_t)row * DD + col] = f2bf(acc[1][mi][ni][r]);
                const int b = row >> 11, s = row & 2047;
                const int h = col >> 6,  dk = col & 63;
                Vo[(((size_t)(b * HH + h)) * 64 + dk) * SS + s] = f2bf(acc[2][mi][ni][r]);
            }
}

// ---------------------------------------------------------------------------
// NT GEMM, 64x64 tile (used for the out-projection only now). BK=32, 4 waves
// 2x2, each wave 32x32 (acc 2x2). A_ASYNC/W_ASYNC: bf16 via global_load_lds |
// fp32 via cvt8. C_F32: fp32 epilogue.
// ---------------------------------------------------------------------------
template<int A_ASYNC, int W_ASYNC, int C_F32>
__global__ __launch_bounds__(256) void gemm_64(
    const void* __restrict__ Ain, const void* __restrict__ W0,
    void* __restrict__ C0)
{
    const int K = DD, N = DD;
    const void* W = W0;
    void* C = C0;

    __shared__ __align__(16) unsigned short As[64 * 32];
    __shared__ __align__(16) unsigned short Bs[64 * 32];

    const int tid  = threadIdx.x;
    const int wave = tid >> 6, lane = tid & 63;
    const int quad = lane >> 4, l16 = lane & 15;
    const int waveM = (wave >> 1) * 32, waveN = (wave & 1) * 32;
    const int m0 = blockIdx.y * 64, n0 = blockIdx.x * 64;

    const int rS = (tid >> 2), cS = (tid & 3) * 8;   // e = tid*8 -> row, col in 64x32 tile

    v4f acc[2][2] = {};

    for (int kt = 0; kt < K; kt += 32) {
        __syncthreads();
        if (A_ASYNC)
            gld_lds16((const unsigned short*)Ain + (size_t)(m0 + rS) * K + kt + cS,
                      &As[wave * 512]);
        else
            *(uint4*)(&As[tid * 8]) = cvt8((const float*)Ain + (size_t)(m0 + rS) * K + kt + cS);
        if (W_ASYNC)
            gld_lds16((const unsigned short*)W + (size_t)(n0 + rS) * K + kt + cS,
                      &Bs[wave * 512]);
        else
            *(uint4*)(&Bs[tid * 8]) = cvt8((const float*)W + (size_t)(n0 + rS) * K + kt + cS);
        __syncthreads();   // drains vm + ds for staging

        v8bf af[2], bf[2];
#pragma unroll
        for (int i = 0; i < 2; ++i) {
            af[i] = *(const v8bf*)(&As[(waveM + i * 16 + l16) * 32 + quad * 8]);
            bf[i] = *(const v8bf*)(&Bs[(waveN + i * 16 + l16) * 32 + quad * 8]);
        }
#pragma unroll
        for (int mi = 0; mi < 2; ++mi)
#pragma unroll
            for (int ni = 0; ni < 2; ++ni)
                acc[mi][ni] = mfma16(af[mi], bf[ni], acc[mi][ni]);
    }

    // Epilogue: C/D layout col=l16, row=quad*4+r (verified formula)
#pragma unroll
    for (int mi = 0; mi < 2; ++mi)
#pragma unroll
        for (int ni = 0; ni < 2; ++ni)
#pragma unroll
            for (int r = 0; r < 4; ++r) {
                int row = m0 + waveM + mi * 16 + quad * 4 + r;
                int col = n0 + waveN + ni * 16 + l16;
                if (C_F32) {
                    ((float*)C)[(size_t)row * N + col] = acc[mi][ni][r];
                } else {
                    ((unsigned short*)C)[(size_t)row * N + col] = f2bf(acc[mi][ni][r]);
                }
            }
}

// ---------------------------------------------------------------------------
// R15 attention (verified): LDS-staged, wave-private q-strips, double-buffered
// K/V via global_load_lds with XOR-swizzle (source-preswizzled), one barrier
// per tile, no merge phase. Unchanged this round.
// ---------------------------------------------------------------------------
__global__ __launch_bounds__(256, 3) void attn_ls(
    const unsigned short* Q,                 // (B,S,D) bf16 (aliases O)
    const unsigned short* __restrict__ Kg,   // (B,S,D) bf16
    const unsigned short* __restrict__ Vt,   // (B,H,64,S) bf16 transposed
    unsigned short* O)                       // (B,S,D) bf16
{
    const int h = blockIdx.x, b = blockIdx.y;
    const int qs = (SS / 64 - 1 - (int)blockIdx.z) * 64;   // LPT: heavy first
    const int tid  = threadIdx.x;
    const int wave = tid >> 6, lane = tid & 63;
    const int quad = lane >> 4, l16 = lane & 15;
    const int qw = qs + wave * 16;           // this wave's private q rows
    const float scale = 0.125f;              // 1/sqrt(64)

    __shared__ __align__(16) unsigned short Ks[2][4096];   // 2 x 64x64 bf16, swizzled
    __shared__ __align__(16) unsigned short Vs[2][4096];   // 2 x 64x64 bf16, swizzled
    __shared__ __align__(16) unsigned short Ps[4][16 * 72];// per-wave P buffer

    // Q frags for this wave's 16 rows (read before any O write: in-place safe)
    v8bf qf0, qf1;
    {
        const unsigned short* qp = &Q[((size_t)(b * SS + qw + l16)) * DD + h * 64];
        qf0 = *(const v8bf*)(qp + quad * 8);
        qf1 = *(const v8bf*)(qp + 32 + quad * 8);
    }

    const int NT = qs / 64 + 1;              // causal k-tiles, SAME for all 4 waves
    const char* kgb = (const char*)&Kg[(size_t)(b * SS) * DD + h * 64];
    const char* vgb = (const char*)&Vt[((size_t)(b * HH + h) * 64) * SS];

    // Staging geometry: per matrix 8192B = 2 chunks x (4 waves x 64 lanes x 16B).
    const int rA = wave * 8 + (lane >> 3);               // rows rA and rA+32
    const int oA = ((lane & 7) * 16) ^ ((rA & 7) << 4);  // swizzled in-row byte
    const int swz = (l16 & 7) << 4;                      // read-side XOR

    v4f oacc[4] = {};
    float l_run[4] = {0.f, 0.f, 0.f, 0.f};
    unsigned short* pw = &Ps[wave][0];

    // Prologue: stage tile 0 into buffer 0
    gld_lds16((const unsigned short*)(kgb + (size_t)rA        * (DD * 2) + oA), &Ks[0][wave * 512]);
    gld_lds16((const unsigned short*)(kgb + (size_t)(rA + 32) * (DD * 2) + oA), &Ks[0][2048 + wave * 512]);
    gld_lds16((const unsigned short*)(vgb + (size_t)rA        * (SS * 2) + oA), &Vs[0][wave * 512]);
    gld_lds16((const unsigned short*)(vgb + (size_t)(rA + 32) * (SS * 2) + oA), &Vs[0][2048 + wave * 512]);
    __syncthreads();   // drains vmcnt: tile 0 resident

    for (int kt = 0; kt < NT; ++kt) {
        const int cur = kt & 1;
        const int kb  = kt * 64;

        // Async-stage NEXT tile into the other buffer
        if (kt + 1 < NT) {
            const size_t kb2 = (size_t)(kb + 64);
            gld_lds16((const unsigned short*)(kgb + (kb2 + rA)      * (DD * 2) + oA), &Ks[cur ^ 1][wave * 512]);
            gld_lds16((const unsigned short*)(kgb + (kb2 + rA + 32) * (DD * 2) + oA), &Ks[cur ^ 1][2048 + wave * 512]);
            gld_lds16((const unsigned short*)(vgb + (size_t)rA        * (SS * 2) + kb2 * 2 + oA), &Vs[cur ^ 1][wave * 512]);
            gld_lds16((const unsigned short*)(vgb + (size_t)(rA + 32) * (SS * 2) + kb2 * 2 + oA), &Vs[cur ^ 1][2048 + wave * 512]);
        }

        const char* ksb = (const char*)&Ks[cur][0];
        const char* vsb = (const char*)&Vs[cur][0];

        // K frags from swizzled LDS: row = nk*16+l16, cols half*32 + quad*8..
        v8bf kf0[4], kf1[4];
#pragma unroll
        for (int nk = 0; nk < 4; ++nk) {
            const char* krow = ksb + (size_t)(nk * 16 + l16) * 128;
            kf0[nk] = *(const v8bf*)(krow + ((quad * 16) ^ swz));
            kf1[nk] = *(const v8bf*)(krow + ((64 + quad * 16) ^ swz));
        }

        // S = Q K^T (16 q-rows x 64 keys), f32 accumulate
        v4f sacc[4] = {};
#pragma unroll
        for (int nk = 0; nk < 4; ++nk) {
            sacc[nk] = mfma16(qf0, kf0[nk], sacc[nk]);
            sacc[nk] = mfma16(qf1, kf1[nk], sacc[nk]);
        }

        // fixed-base softmax: p = exp(s/8); mask only on the diagonal tile
        const bool diag = (kt == NT - 1);
        float pv[4][4];
#pragma unroll
        for (int nk = 0; nk < 4; ++nk)
#pragma unroll
            for (int r = 0; r < 4; ++r) {
                float p = __expf(sacc[nk][r] * scale);
                if (diag) {
                    int key  = kb + nk * 16 + l16;
                    int qrow = qw + quad * 4 + r;
                    if (key > qrow) p = 0.0f;
                }
                pv[nk][r] = p;
                l_run[r] += p;
            }

        // V frags (issued before the P round-trip so latency overlaps it)
        v8bf vf[2][4];
#pragma unroll
        for (int kc = 0; kc < 2; ++kc)
#pragma unroll
            for (int dt = 0; dt < 4; ++dt) {
                const char* vr = vsb + (size_t)(dt * 16 + l16) * 128;
                vf[kc][dt] = *(const v8bf*)(vr + ((kc * 64 + quad * 16) ^ swz));
            }

        // P: C-layout -> per-wave LDS (stride 72) -> A-layout frags
#pragma unroll
        for (int nk = 0; nk < 4; ++nk)
#pragma unroll
            for (int r = 0; r < 4; ++r)
                pw[(quad * 4 + r) * 72 + nk * 16 + l16] = f2bf(pv[nk][r]);
        __asm__ volatile("" ::: "memory");

        v8bf pa0 = *(const v8bf*)(&pw[l16 * 72 + quad * 8]);
        v8bf pa1 = *(const v8bf*)(&pw[l16 * 72 + 32 + quad * 8]);
#pragma unroll
        for (int dt = 0; dt < 4; ++dt) oacc[dt] = mfma16(pa0, vf[0][dt], oacc[dt]);
#pragma unroll
        for (int dt = 0; dt < 4; ++dt) oacc[dt] = mfma16(pa1, vf[1][dt], oacc[dt]);

        // One barrier per tile: reads of buf[cur] done + buf[cur^1] resident.
        __syncthreads();
    }

    // Row-sum reduce across the 16 l16-lanes of each quad
    for (int off = 1; off < 16; off <<= 1)
#pragma unroll
        for (int r = 0; r < 4; ++r)
            l_run[r] += __shfl_xor(l_run[r], off, 64);

    float inv[4];
#pragma unroll
    for (int r = 0; r < 4; ++r) inv[r] = 1.0f / l_run[r];

    // Direct per-wave store: lane holds O[qw+quad*4+r][dt*16+l16] (C layout).
    unsigned short* ob = &O[((size_t)(b * SS + qw + quad * 4)) * DD + h * 64 + l16];
#pragma unroll
    for (int r = 0; r < 4; ++r)
#pragma unroll
        for (int dt = 0; dt < 4; ++dt)
            ob[(size_t)r * DD + dt * 16] = f2bf(oacc[dt][r] * inv[r]);
}

// ---------------------------------------------------------------------------
extern "C" void kernel_launch(void* const* d_in, const int* in_sizes, int n_in,
                              void* d_out, int out_size, void* d_ws, size_t ws_size,
                              hipStream_t stream)
{
    const float* X  = (const float*)d_in[0];
    const float* Wq = (const float*)d_in[1];
    const float* Wk = (const float*)d_in[2];
    const float* Wv = (const float*)d_in[3];
    const float* Wo = (const float*)d_in[4];
    float* Out = (float*)d_out;

    // d_ws (verified >= 12.6 MB): Qb, Kb bf16. Kb is dead after attn; cvt_wo
    // reuses it for bf16 Wo.
    // d_out (12.58 MB as 2*XSZ u16 slots): [0,XSZ) = V^T bf16 (dead before
    // gemm3 writes); [XSZ, XSZ+3*WSZ) = bf16 Wq,Wk,Wv (dead after gemm1).
    unsigned short* Qb  = (unsigned short*)d_ws;
    unsigned short* Kb  = Qb + XSZ;
    unsigned short* Vtb = (unsigned short*)d_out;
    unsigned short* Wqb = Vtb + XSZ;
    unsigned short* Wkb = Wqb + WSZ;
    unsigned short* Wvb = Wkb + WSZ;

    dim3 blk(256);
    cvt_w3<<<1728, blk, 0, stream>>>(Wq, Wk, Wv, Wqb);

    dim3 g1(DD / 64, MM / 64);                      // 768 blocks: fused QKV
    gemm_qkv<<<g1, blk, 0, stream>>>(X, Wqb, Wkb, Wvb, Qb, Kb, Vtb);

    dim3 g2(HH, BB, SS / 64);                       // 768 blocks: LDS-staged attn
    attn_ls<<<g2, blk, 0, stream>>>(Qb, Kb, Vtb, Qb);

    cvt_wo<<<576, blk, 0, stream>>>(Wo, Kb);        // Kb dead after attn

    dim3 g3(DD / 64, MM / 64);                      // 768 blocks: out projection
    gemm_64<1, 1, 1><<<g3, blk, 0, stream>>>(Qb, Kb, Out);
}